// Round 10
// baseline (211.375 us; speedup 1.0000x reference)
//
#include <hip/hip_runtime.h>

#define NN 50000
#define NE 600000
#define MAXD 64
#define ZB ((NN + 255) / 256)    // 196 zero blocks
#define GB ((NN + 63) / 64)      // 782 gemm blocks

typedef __attribute__((ext_vector_type(8))) short short8;   // 8 bf16 = 4 VGPR
typedef __attribute__((ext_vector_type(4))) float floatx4;  // MFMA acc

__device__ __forceinline__ float b2f(unsigned short u) {
    return __uint_as_float((unsigned)u << 16);
}
__device__ __forceinline__ unsigned short f2b(float f) {
    unsigned u = __float_as_uint(f);
    return (unsigned short)((u + 0x7FFF + ((u >> 16) & 1)) >> 16);
}

// ---------------------------------------------------------------------------
// Fused init: blocks [0,152) convert weights fp32->bf16 into Wb
// ([0,16384) W1b | [16384,32768) W2b | [32768,38912) Wfcb 48 rows, 40..47
// zero); blocks [152,152+ZB) zero the ELL counts.
// ---------------------------------------------------------------------------
__global__ __launch_bounds__(256) void init_k(
    const float* __restrict__ W1, const float* __restrict__ W2,
    const float* __restrict__ Wfc, unsigned short* __restrict__ Wb,
    int* __restrict__ counts)
{
    int blk = blockIdx.x;
    int t = threadIdx.x;
    if (blk < 152) {
        int id = blk * 256 + t;
        if (id < 16384) {
            Wb[id] = f2b(W1[id]);
        } else if (id < 32768) {
            Wb[id] = f2b(W2[id - 16384]);
        } else {
            int k = id - 32768;
            int r = k >> 7, c = k & 127;
            Wb[id] = (r < 40) ? f2b(Wfc[r * 128 + c]) : (unsigned short)0;
        }
    } else {
        int i = (blk - 152) * 256 + t;
        if (i < NN) counts[i] = 0;
    }
}

// ---------------------------------------------------------------------------
// Layer-1 GEMM with ELL fill hidden inside each thread:
//  - at entry: load 3 edges' (src,dst) (independent, coalesced) — their
//    latency is hidden under the GEMM staging + MFMA work;
//  - GEMM: Y[n][j] = bf16(relu(sum_k X[n][k]*W[j][k] + b[j]));
//  - epilogue: 3 independent atomicAdd+scatter chains complete the ELL.
// R8/R9 lesson: never co-dispatch latency-bound block populations with
// LDS-heavy ones — hide the latency work INSIDE the compute threads.
// ---------------------------------------------------------------------------
__global__ __launch_bounds__(256) void gemmfill_k(
    const float* __restrict__ X, const unsigned short* __restrict__ Wb,
    const float* __restrict__ b, unsigned short* __restrict__ Y,
    const int* __restrict__ src, const int* __restrict__ dst,
    int* __restrict__ counts, int* __restrict__ slot, int N, int E)
{
    __shared__ __align__(16) unsigned short Xs[64 * 136];
    __shared__ __align__(16) unsigned short Ws[128 * 136];
    const int t  = threadIdx.x;
    const int n0 = blockIdx.x * 64;
    const int gid = blockIdx.x * 256 + t;
    const int STRIDE = GB * 256;          // 200192 threads

    // issue edge loads first; results not needed until the epilogue
    int e0 = gid, e1 = gid + STRIDE, e2 = gid + 2 * STRIDE;
    int s0 = 0, d0 = -1, s1 = 0, d1 = -1, s2 = 0, d2 = -1;
    if (e0 < E) { s0 = src[e0]; d0 = dst[e0]; }
    if (e1 < E) { s1 = src[e1]; d1 = dst[e1]; }
    if (e2 < E) { s2 = src[e2]; d2 = dst[e2]; }

    // ---- GEMM staging ----
#pragma unroll
    for (int i = 0; i < 8; ++i) {
        int f = t + i * 256;
        int r = f >> 5, kq = f & 31;
        float4 v = make_float4(0.f, 0.f, 0.f, 0.f);
        if (n0 + r < N) v = ((const float4*)(X + (size_t)(n0 + r) * 128))[kq];
        *(ushort4*)&Xs[r * 136 + kq * 4] =
            make_ushort4(f2b(v.x), f2b(v.y), f2b(v.z), f2b(v.w));
    }
#pragma unroll
    for (int i = 0; i < 8; ++i) {
        int f = t + i * 256;
        int r = f >> 4, c = f & 15;
        *(short8*)&Ws[r * 136 + c * 8] = *(const short8*)(Wb + r * 128 + c * 8);
    }
    __syncthreads();

    const int w = t >> 6, lane = t & 63;
    const int m = lane & 15, q = lane >> 4;

    short8 a[4];
#pragma unroll
    for (int kc = 0; kc < 4; ++kc)
        a[kc] = *(const short8*)&Xs[(16 * w + m) * 136 + kc * 32 + q * 8];

    floatx4 acc[8];
#pragma unroll
    for (int jt = 0; jt < 8; ++jt) {
        floatx4 c = {0.f, 0.f, 0.f, 0.f};
#pragma unroll
        for (int kc = 0; kc < 4; ++kc) {
            short8 bb = *(const short8*)&Ws[(16 * jt + m) * 136 + kc * 32 + q * 8];
            c = __builtin_amdgcn_mfma_f32_16x16x32_bf16(a[kc], bb, c, 0, 0, 0);
        }
        acc[jt] = c;
    }

    // D layout: col = lane&15, row = (lane>>4)*4 + reg
#pragma unroll
    for (int jt = 0; jt < 8; ++jt) {
        int j = 16 * jt + m;
        float bj = b[j];
#pragma unroll
        for (int r = 0; r < 4; ++r) {
            int node = n0 + 16 * w + q * 4 + r;
            if (node < N) {
                float v = acc[jt][r] + bj;
                Y[(size_t)node * 128 + j] = f2b(v > 0.f ? v : 0.f);
            }
        }
    }

    // ---- ELL fill epilogue (3 independent chains) ----
    if (d0 >= 0) {
        int p = atomicAdd(&counts[d0], 1);
        if (p < MAXD) slot[d0 * MAXD + p] = s0;
    }
    if (d1 >= 0) {
        int p = atomicAdd(&counts[d1], 1);
        if (p < MAXD) slot[d1 * MAXD + p] = s1;
    }
    if (d2 >= 0) {
        int p = atomicAdd(&counts[d2], 1);
        if (p < MAXD) slot[d2 * MAXD + p] = s2;
    }
}

// ---------------------------------------------------------------------------
// Fused GEMM2 + FC (standalone; gathers stay separate for occupancy):
//   h = relu(Xb W2^T + b2) [kept in LDS, bf16];
//   G[n][j] = bf16(sum_k h[n][k]*Wfc[j][k]), j<40, stride 64.
// ---------------------------------------------------------------------------
__global__ __launch_bounds__(256) void gemm2fc_k(
    const unsigned short* __restrict__ Xb, const unsigned short* __restrict__ W2b,
    const float* __restrict__ b2, const unsigned short* __restrict__ Wfcb,
    unsigned short* __restrict__ G, int N)
{
    __shared__ __align__(16) unsigned short Xs[64 * 136];
    __shared__ __align__(16) unsigned short Ws[128 * 136];
    const int t  = threadIdx.x;
    const int n0 = blockIdx.x * 64;

#pragma unroll
    for (int i = 0; i < 4; ++i) {
        int f = t + i * 256;
        int r = f >> 4, c = f & 15;
        short8 v = {0, 0, 0, 0, 0, 0, 0, 0};
        if (n0 + r < N)
            v = *(const short8*)(Xb + (size_t)(n0 + r) * 128 + c * 8);
        *(short8*)&Xs[r * 136 + c * 8] = v;
    }
#pragma unroll
    for (int i = 0; i < 8; ++i) {
        int f = t + i * 256;
        int r = f >> 4, c = f & 15;
        *(short8*)&Ws[r * 136 + c * 8] = *(const short8*)(W2b + r * 128 + c * 8);
    }
    __syncthreads();

    const int w = t >> 6, lane = t & 63;
    const int m = lane & 15, q = lane >> 4;

    short8 a[4];
#pragma unroll
    for (int kc = 0; kc < 4; ++kc)
        a[kc] = *(const short8*)&Xs[(16 * w + m) * 136 + kc * 32 + q * 8];

    floatx4 acc[8];
#pragma unroll
    for (int jt = 0; jt < 8; ++jt) {
        floatx4 c = {0.f, 0.f, 0.f, 0.f};
#pragma unroll
        for (int kc = 0; kc < 4; ++kc) {
            short8 bb = *(const short8*)&Ws[(16 * jt + m) * 136 + kc * 32 + q * 8];
            c = __builtin_amdgcn_mfma_f32_16x16x32_bf16(a[kc], bb, c, 0, 0, 0);
        }
        acc[jt] = c;
    }

    // relu(acc + b2) -> bf16 -> back into Xs (each wave owns rows 16w..16w+15)
#pragma unroll
    for (int jt = 0; jt < 8; ++jt) {
        int j = 16 * jt + m;
        float bj = b2[j];
#pragma unroll
        for (int r = 0; r < 4; ++r) {
            float v = acc[jt][r] + bj;
            Xs[(16 * w + q * 4 + r) * 136 + j] = f2b(v > 0.f ? v : 0.f);
        }
    }
    __syncthreads();

    // re-stage Wfc (48 rows) over Ws
#pragma unroll
    for (int i = 0; i < 3; ++i) {
        int f = t + i * 256;
        int r = f >> 4, c = f & 15;
        *(short8*)&Ws[r * 136 + c * 8] = *(const short8*)(Wfcb + r * 128 + c * 8);
    }
    __syncthreads();

    short8 a2[4];
#pragma unroll
    for (int kc = 0; kc < 4; ++kc)
        a2[kc] = *(const short8*)&Xs[(16 * w + m) * 136 + kc * 32 + q * 8];

#pragma unroll
    for (int jt = 0; jt < 3; ++jt) {
        floatx4 c = {0.f, 0.f, 0.f, 0.f};
#pragma unroll
        for (int kc = 0; kc < 4; ++kc) {
            short8 bb = *(const short8*)&Ws[(16 * jt + m) * 136 + kc * 32 + q * 8];
            c = __builtin_amdgcn_mfma_f32_16x16x32_bf16(a2[kc], bb, c, 0, 0, 0);
        }
        int j = 16 * jt + m;
        if (j < 40) {
#pragma unroll
            for (int r = 0; r < 4; ++r) {
                int node = n0 + 16 * w + q * 4 + r;
                if (node < N) G[(size_t)node * 64 + j] = f2b(c[r]);
            }
        }
    }
}

// ---------------------------------------------------------------------------
// Gather-sum 128-wide (bf16 in/out), ELL. One wave per node; 4 edge slots
// (16 lanes x ushort8), unroll x2 -> 8 row loads in flight. Standalone:
// needs max occupancy (R8/R9 lesson).
// ---------------------------------------------------------------------------
__global__ __launch_bounds__(256) void agg128_k(
    const unsigned short* __restrict__ H, const int* __restrict__ counts,
    const int* __restrict__ slot, unsigned short* __restrict__ X, int N)
{
    int node = (blockIdx.x * 256 + threadIdx.x) >> 6;
    int lane = threadIdx.x & 63;
    if (node >= N) return;
    int e4 = lane >> 4;
    int c8 = lane & 15;
    int beg = node * MAXD;
    int end = beg + min(counts[node], MAXD);
    float acc[8] = {};

    int i = beg + e4;
    for (; i + 4 < end; i += 8) {
        int s0 = slot[i], s1 = slot[i + 4];
        short8 a = *(const short8*)(H + (size_t)s0 * 128 + c8 * 8);
        short8 b = *(const short8*)(H + (size_t)s1 * 128 + c8 * 8);
#pragma unroll
        for (int j = 0; j < 8; ++j)
            acc[j] += b2f((unsigned short)a[j]) + b2f((unsigned short)b[j]);
    }
    if (i < end) {
        int s0 = slot[i];
        short8 a = *(const short8*)(H + (size_t)s0 * 128 + c8 * 8);
#pragma unroll
        for (int j = 0; j < 8; ++j)
            acc[j] += b2f((unsigned short)a[j]);
    }
#pragma unroll
    for (int j = 0; j < 8; ++j) {
        acc[j] += __shfl(acc[j], lane ^ 16);
        acc[j] += __shfl(acc[j], lane ^ 32);
    }
    if (e4 == 0) {
        short8 o;
#pragma unroll
        for (int j = 0; j < 8; ++j) o[j] = (short)f2b(acc[j]);
        *(short8*)(X + (size_t)node * 128 + c8 * 8) = o;
    }
}

// ---------------------------------------------------------------------------
// Gather-sum 40-wide + bias (bf16 in stride 64, fp32 out), ELL.
// 8 edge slots x 8 lanes (ushort8 = full 128B row), unroll x2 -> 16 row
// loads in flight. Butterfly across lane^8, ^16, ^32.
// ---------------------------------------------------------------------------
__global__ __launch_bounds__(256) void agg40_k(
    const unsigned short* __restrict__ G, const int* __restrict__ counts,
    const int* __restrict__ slot, const float* __restrict__ bfc,
    float* __restrict__ OUT, int N)
{
    int node = (blockIdx.x * 256 + threadIdx.x) >> 6;
    int lane = threadIdx.x & 63;
    if (node >= N) return;
    int e8 = lane >> 3;            // edge slot group 0..7
    int c8 = lane & 7;             // cols 8*c8..8*c8+7 (c8<5 meaningful)
    int beg = node * MAXD;
    int end = beg + min(counts[node], MAXD);
    float acc[8] = {};

    int i = beg + e8;
    for (; i + 8 < end; i += 16) {
        int s0 = slot[i], s1 = slot[i + 8];
        short8 a = *(const short8*)(G + (size_t)s0 * 64 + c8 * 8);
        short8 b = *(const short8*)(G + (size_t)s1 * 64 + c8 * 8);
#pragma unroll
        for (int j = 0; j < 8; ++j)
            acc[j] += b2f((unsigned short)a[j]) + b2f((unsigned short)b[j]);
    }
    if (i < end) {
        int s0 = slot[i];
        short8 a = *(const short8*)(G + (size_t)s0 * 64 + c8 * 8);
#pragma unroll
        for (int j = 0; j < 8; ++j)
            acc[j] += b2f((unsigned short)a[j]);
    }
#pragma unroll
    for (int j = 0; j < 8; ++j) {
        acc[j] += __shfl(acc[j], lane ^ 8);
        acc[j] += __shfl(acc[j], lane ^ 16);
        acc[j] += __shfl(acc[j], lane ^ 32);
    }
    if (e8 == 0 && c8 < 5) {
        float* p = OUT + (size_t)node * 40 + c8 * 8;
        *(float4*)p = make_float4(acc[0] + bfc[c8 * 8 + 0],
                                  acc[1] + bfc[c8 * 8 + 1],
                                  acc[2] + bfc[c8 * 8 + 2],
                                  acc[3] + bfc[c8 * 8 + 3]);
        *(float4*)(p + 4) = make_float4(acc[4] + bfc[c8 * 8 + 4],
                                        acc[5] + bfc[c8 * 8 + 5],
                                        acc[6] + bfc[c8 * 8 + 6],
                                        acc[7] + bfc[c8 * 8 + 7]);
    }
}

extern "C" void kernel_launch(void* const* d_in, const int* in_sizes, int n_in,
                              void* d_out, int out_size, void* d_ws, size_t ws_size,
                              hipStream_t stream)
{
    const float* X    = (const float*)d_in[0];
    const float* W1   = (const float*)d_in[1];
    const float* b1   = (const float*)d_in[2];
    const float* W2   = (const float*)d_in[3];
    const float* b2   = (const float*)d_in[4];
    const float* Wfc  = (const float*)d_in[5];
    const float* bfc  = (const float*)d_in[6];
    const int*   esrc = (const int*)d_in[7];
    const int*   edst = (const int*)d_in[8];
    float* out = (float*)d_out;

    // Workspace layout (~38.7 MB):
    unsigned short* h   = (unsigned short*)d_ws;        // bf16 [NN,128]
    unsigned short* x1b = h + (size_t)NN * 128;         // bf16 [NN,128]
    unsigned short* g   = h;                            // bf16 [NN,64] alias
                                                        //  (h dead after agg128)
    int* counts = (int*)(x1b + (size_t)NN * 128);       // NN
    int* slot   = counts + NN;                          // NN*MAXD
    unsigned short* Wb = (unsigned short*)(slot + (size_t)NN * MAXD); // 38912

    // 1. fused init: weights->bf16 + zero ELL counts
    init_k<<<152 + ZB, 256, 0, stream>>>(W1, W2, Wfc, Wb, counts);
    // 2. layer-1 GEMM with ELL fill hidden in the same threads
    gemmfill_k<<<GB, 256, 0, stream>>>(X, Wb, b1, h, esrc, edst,
                                       counts, slot, NN, NE);
    // 3. aggregate 128-wide -> x1b
    agg128_k<<<(NN * 64) / 256, 256, 0, stream>>>(h, counts, slot, x1b, NN);
    // 4. fused layer-2 GEMM + FC -> g
    gemm2fc_k<<<GB, 256, 0, stream>>>(x1b, Wb + 16384, b2, Wb + 32768, g, NN);
    // 5. aggregate 40-wide + bias -> out
    agg40_k<<<(NN * 64) / 256, 256, 0, stream>>>(g, counts, slot, bfc, out, NN);
}

// Round 11
// 187.725 us; speedup vs baseline: 1.1260x; 1.1260x over previous
//
#include <hip/hip_runtime.h>

#define NN 50000
#define NE 600000
#define MAXD 64
#define GB ((NN + 63) / 64)      // 782 gemm blocks
#define FB ((NE + 255) / 256)    // 2344 fill blocks

typedef __attribute__((ext_vector_type(8))) short short8;   // 8 bf16 = 4 VGPR
typedef __attribute__((ext_vector_type(4))) float floatx4;  // MFMA acc

__device__ __forceinline__ float b2f(unsigned short u) {
    return __uint_as_float((unsigned)u << 16);
}
__device__ __forceinline__ unsigned short f2b(float f) {
    unsigned u = __float_as_uint(f);
    return (unsigned short)((u + 0x7FFF + ((u >> 16) & 1)) >> 16);
}

// ---------------------------------------------------------------------------
// Fused init + ELL fill (both 0-LDS, latency-tolerant — the resource-matched
// co-dispatch that R8/R9's LDS-heavy fusions were not):
//   blocks [0,152): convert weights fp32->bf16 into Wb
//     ([0,16384) W1b | [16384,32768) W2b | [32768,38912) Wfcb, rows 40..47 0)
//   blocks [152,152+FB): ELL fill slot[d*MAXD+p]=s (counts pre-zeroed by
//     hipMemsetAsync).
// ---------------------------------------------------------------------------
__global__ __launch_bounds__(256) void initfill_k(
    const float* __restrict__ W1, const float* __restrict__ W2,
    const float* __restrict__ Wfc, unsigned short* __restrict__ Wb,
    const int* __restrict__ src, const int* __restrict__ dst,
    int* __restrict__ counts, int* __restrict__ slot, int E)
{
    int blk = blockIdx.x;
    int t = threadIdx.x;
    if (blk < 152) {
        int id = blk * 256 + t;
        if (id < 16384) {
            Wb[id] = f2b(W1[id]);
        } else if (id < 32768) {
            Wb[id] = f2b(W2[id - 16384]);
        } else {
            int k = id - 32768;
            int r = k >> 7, c = k & 127;
            Wb[id] = (r < 40) ? f2b(Wfc[r * 128 + c]) : (unsigned short)0;
        }
    } else {
        int id = (blk - 152) * 256 + t;
        if (id < E) {
            int d = dst[id], s = src[id];
            int p = atomicAdd(&counts[d], 1);
            if (p < MAXD) slot[d * MAXD + p] = s;
        }
    }
}

// ---------------------------------------------------------------------------
// MFMA GEMM + bias + relu, fp32 X input, bf16 W:
//   Y[n][j] = bf16(relu(sum_k X[n][k]*W[j][k] + b[j]))
// 256 thr = 4 waves, 64 nodes x 128 j; wave: 16 nodes, 8 j-tiles, 4 k-chunks.
// ---------------------------------------------------------------------------
__global__ __launch_bounds__(256) void gemm_mfma_f32in_k(
    const float* __restrict__ X, const unsigned short* __restrict__ Wb,
    const float* __restrict__ b, unsigned short* __restrict__ Y, int N)
{
    __shared__ __align__(16) unsigned short Xs[64 * 136];
    __shared__ __align__(16) unsigned short Ws[128 * 136];
    const int t  = threadIdx.x;
    const int n0 = blockIdx.x * 64;

#pragma unroll
    for (int i = 0; i < 8; ++i) {
        int f = t + i * 256;
        int r = f >> 5, kq = f & 31;
        float4 v = make_float4(0.f, 0.f, 0.f, 0.f);
        if (n0 + r < N) v = ((const float4*)(X + (size_t)(n0 + r) * 128))[kq];
        *(ushort4*)&Xs[r * 136 + kq * 4] =
            make_ushort4(f2b(v.x), f2b(v.y), f2b(v.z), f2b(v.w));
    }
#pragma unroll
    for (int i = 0; i < 8; ++i) {
        int f = t + i * 256;
        int r = f >> 4, c = f & 15;
        *(short8*)&Ws[r * 136 + c * 8] = *(const short8*)(Wb + r * 128 + c * 8);
    }
    __syncthreads();

    const int w = t >> 6, lane = t & 63;
    const int m = lane & 15, q = lane >> 4;

    short8 a[4];
#pragma unroll
    for (int kc = 0; kc < 4; ++kc)
        a[kc] = *(const short8*)&Xs[(16 * w + m) * 136 + kc * 32 + q * 8];

    floatx4 acc[8];
#pragma unroll
    for (int jt = 0; jt < 8; ++jt) {
        floatx4 c = {0.f, 0.f, 0.f, 0.f};
#pragma unroll
        for (int kc = 0; kc < 4; ++kc) {
            short8 bb = *(const short8*)&Ws[(16 * jt + m) * 136 + kc * 32 + q * 8];
            c = __builtin_amdgcn_mfma_f32_16x16x32_bf16(a[kc], bb, c, 0, 0, 0);
        }
        acc[jt] = c;
    }

    // D layout: col = lane&15, row = (lane>>4)*4 + reg
#pragma unroll
    for (int jt = 0; jt < 8; ++jt) {
        int j = 16 * jt + m;
        float bj = b[j];
#pragma unroll
        for (int r = 0; r < 4; ++r) {
            int node = n0 + 16 * w + q * 4 + r;
            if (node < N) {
                float v = acc[jt][r] + bj;
                Y[(size_t)node * 128 + j] = f2b(v > 0.f ? v : 0.f);
            }
        }
    }
}

// ---------------------------------------------------------------------------
// Fused GEMM2 + FC (standalone; gathers stay separate for occupancy):
//   h = relu(Xb W2^T + b2) [kept in LDS, bf16];
//   G[n][j] = bf16(sum_k h[n][k]*Wfc[j][k]), j<40, stride 64.
// ---------------------------------------------------------------------------
__global__ __launch_bounds__(256) void gemm2fc_k(
    const unsigned short* __restrict__ Xb, const unsigned short* __restrict__ W2b,
    const float* __restrict__ b2, const unsigned short* __restrict__ Wfcb,
    unsigned short* __restrict__ G, int N)
{
    __shared__ __align__(16) unsigned short Xs[64 * 136];
    __shared__ __align__(16) unsigned short Ws[128 * 136];
    const int t  = threadIdx.x;
    const int n0 = blockIdx.x * 64;

#pragma unroll
    for (int i = 0; i < 4; ++i) {
        int f = t + i * 256;
        int r = f >> 4, c = f & 15;
        short8 v = {0, 0, 0, 0, 0, 0, 0, 0};
        if (n0 + r < N)
            v = *(const short8*)(Xb + (size_t)(n0 + r) * 128 + c * 8);
        *(short8*)&Xs[r * 136 + c * 8] = v;
    }
#pragma unroll
    for (int i = 0; i < 8; ++i) {
        int f = t + i * 256;
        int r = f >> 4, c = f & 15;
        *(short8*)&Ws[r * 136 + c * 8] = *(const short8*)(W2b + r * 128 + c * 8);
    }
    __syncthreads();

    const int w = t >> 6, lane = t & 63;
    const int m = lane & 15, q = lane >> 4;

    short8 a[4];
#pragma unroll
    for (int kc = 0; kc < 4; ++kc)
        a[kc] = *(const short8*)&Xs[(16 * w + m) * 136 + kc * 32 + q * 8];

    floatx4 acc[8];
#pragma unroll
    for (int jt = 0; jt < 8; ++jt) {
        floatx4 c = {0.f, 0.f, 0.f, 0.f};
#pragma unroll
        for (int kc = 0; kc < 4; ++kc) {
            short8 bb = *(const short8*)&Ws[(16 * jt + m) * 136 + kc * 32 + q * 8];
            c = __builtin_amdgcn_mfma_f32_16x16x32_bf16(a[kc], bb, c, 0, 0, 0);
        }
        acc[jt] = c;
    }

    // relu(acc + b2) -> bf16 -> back into Xs (each wave owns rows 16w..16w+15)
#pragma unroll
    for (int jt = 0; jt < 8; ++jt) {
        int j = 16 * jt + m;
        float bj = b2[j];
#pragma unroll
        for (int r = 0; r < 4; ++r) {
            float v = acc[jt][r] + bj;
            Xs[(16 * w + q * 4 + r) * 136 + j] = f2b(v > 0.f ? v : 0.f);
        }
    }
    __syncthreads();

    // re-stage Wfc (48 rows) over Ws
#pragma unroll
    for (int i = 0; i < 3; ++i) {
        int f = t + i * 256;
        int r = f >> 4, c = f & 15;
        *(short8*)&Ws[r * 136 + c * 8] = *(const short8*)(Wfcb + r * 128 + c * 8);
    }
    __syncthreads();

    short8 a2[4];
#pragma unroll
    for (int kc = 0; kc < 4; ++kc)
        a2[kc] = *(const short8*)&Xs[(16 * w + m) * 136 + kc * 32 + q * 8];

#pragma unroll
    for (int jt = 0; jt < 3; ++jt) {
        floatx4 c = {0.f, 0.f, 0.f, 0.f};
#pragma unroll
        for (int kc = 0; kc < 4; ++kc) {
            short8 bb = *(const short8*)&Ws[(16 * jt + m) * 136 + kc * 32 + q * 8];
            c = __builtin_amdgcn_mfma_f32_16x16x32_bf16(a2[kc], bb, c, 0, 0, 0);
        }
        int j = 16 * jt + m;
        if (j < 40) {
#pragma unroll
            for (int r = 0; r < 4; ++r) {
                int node = n0 + 16 * w + q * 4 + r;
                if (node < N) G[(size_t)node * 64 + j] = f2b(c[r]);
            }
        }
    }
}

// ---------------------------------------------------------------------------
// Gather-sum 128-wide (bf16 in/out), ELL. One wave per node; 4 edge-slot
// groups x 16 lanes (ushort8 = 128 cols). Predicated 4-deep batch: up to 4
// independent row loads in flight per group (covers deg<=16 in one batch;
// invalid slots fall back to s0's address, masked by 0/1 fma). Standalone:
// needs max occupancy (R8/R9/R10 lesson).
// ---------------------------------------------------------------------------
__global__ __launch_bounds__(256) void agg128_k(
    const unsigned short* __restrict__ H, const int* __restrict__ counts,
    const int* __restrict__ slot, unsigned short* __restrict__ X, int N)
{
    int node = (blockIdx.x * 256 + threadIdx.x) >> 6;
    int lane = threadIdx.x & 63;
    if (node >= N) return;
    int e4 = lane >> 4;
    int c8 = lane & 15;
    int beg = node * MAXD;
    int end = beg + min(counts[node], MAXD);
    float acc[8] = {};

    for (int i = beg + e4; i < end; i += 16) {
        bool v1 = i + 4 < end, v2 = i + 8 < end, v3 = i + 12 < end;
        int s0 = slot[i];
        int s1 = v1 ? slot[i + 4]  : s0;
        int s2 = v2 ? slot[i + 8]  : s0;
        int s3 = v3 ? slot[i + 12] : s0;
        short8 r0 = *(const short8*)(H + (size_t)s0 * 128 + c8 * 8);
        short8 r1 = *(const short8*)(H + (size_t)s1 * 128 + c8 * 8);
        short8 r2 = *(const short8*)(H + (size_t)s2 * 128 + c8 * 8);
        short8 r3 = *(const short8*)(H + (size_t)s3 * 128 + c8 * 8);
        float m1 = v1 ? 1.f : 0.f, m2 = v2 ? 1.f : 0.f, m3 = v3 ? 1.f : 0.f;
#pragma unroll
        for (int j = 0; j < 8; ++j) {
            acc[j] += b2f((unsigned short)r0[j]);
            acc[j] += m1 * b2f((unsigned short)r1[j]);
            acc[j] += m2 * b2f((unsigned short)r2[j]);
            acc[j] += m3 * b2f((unsigned short)r3[j]);
        }
    }
#pragma unroll
    for (int j = 0; j < 8; ++j) {
        acc[j] += __shfl(acc[j], lane ^ 16);
        acc[j] += __shfl(acc[j], lane ^ 32);
    }
    if (e4 == 0) {
        short8 o;
#pragma unroll
        for (int j = 0; j < 8; ++j) o[j] = (short)f2b(acc[j]);
        *(short8*)(X + (size_t)node * 128 + c8 * 8) = o;
    }
}

// ---------------------------------------------------------------------------
// Gather-sum 40-wide + bias (bf16 in stride 64, fp32 out), ELL.
// 8 edge-slot groups x 8 lanes (ushort8 = full row). Predicated 2-deep batch.
// ---------------------------------------------------------------------------
__global__ __launch_bounds__(256) void agg40_k(
    const unsigned short* __restrict__ G, const int* __restrict__ counts,
    const int* __restrict__ slot, const float* __restrict__ bfc,
    float* __restrict__ OUT, int N)
{
    int node = (blockIdx.x * 256 + threadIdx.x) >> 6;
    int lane = threadIdx.x & 63;
    if (node >= N) return;
    int e8 = lane >> 3;            // edge-slot group 0..7
    int c8 = lane & 7;             // cols 8*c8..8*c8+7 (c8<5 meaningful)
    int beg = node * MAXD;
    int end = beg + min(counts[node], MAXD);
    float acc[8] = {};

    for (int i = beg + e8; i < end; i += 16) {
        bool v1 = i + 8 < end;
        int s0 = slot[i];
        int s1 = v1 ? slot[i + 8] : s0;
        short8 r0 = *(const short8*)(G + (size_t)s0 * 64 + c8 * 8);
        short8 r1 = *(const short8*)(G + (size_t)s1 * 64 + c8 * 8);
        float m1 = v1 ? 1.f : 0.f;
#pragma unroll
        for (int j = 0; j < 8; ++j) {
            acc[j] += b2f((unsigned short)r0[j]);
            acc[j] += m1 * b2f((unsigned short)r1[j]);
        }
    }
#pragma unroll
    for (int j = 0; j < 8; ++j) {
        acc[j] += __shfl(acc[j], lane ^ 8);
        acc[j] += __shfl(acc[j], lane ^ 16);
        acc[j] += __shfl(acc[j], lane ^ 32);
    }
    if (e8 == 0 && c8 < 5) {
        float* p = OUT + (size_t)node * 40 + c8 * 8;
        *(float4*)p = make_float4(acc[0] + bfc[c8 * 8 + 0],
                                  acc[1] + bfc[c8 * 8 + 1],
                                  acc[2] + bfc[c8 * 8 + 2],
                                  acc[3] + bfc[c8 * 8 + 3]);
        *(float4*)(p + 4) = make_float4(acc[4] + bfc[c8 * 8 + 4],
                                        acc[5] + bfc[c8 * 8 + 5],
                                        acc[6] + bfc[c8 * 8 + 6],
                                        acc[7] + bfc[c8 * 8 + 7]);
    }
}

extern "C" void kernel_launch(void* const* d_in, const int* in_sizes, int n_in,
                              void* d_out, int out_size, void* d_ws, size_t ws_size,
                              hipStream_t stream)
{
    const float* X    = (const float*)d_in[0];
    const float* W1   = (const float*)d_in[1];
    const float* b1   = (const float*)d_in[2];
    const float* W2   = (const float*)d_in[3];
    const float* b2   = (const float*)d_in[4];
    const float* Wfc  = (const float*)d_in[5];
    const float* bfc  = (const float*)d_in[6];
    const int*   esrc = (const int*)d_in[7];
    const int*   edst = (const int*)d_in[8];
    float* out = (float*)d_out;

    // Workspace layout (~38.7 MB):
    unsigned short* h   = (unsigned short*)d_ws;        // bf16 [NN,128]
    unsigned short* x1b = h + (size_t)NN * 128;         // bf16 [NN,128]
    unsigned short* g   = h;                            // bf16 [NN,64] alias
                                                        //  (h dead after agg128)
    int* counts = (int*)(x1b + (size_t)NN * 128);       // NN
    int* slot   = counts + NN;                          // NN*MAXD
    unsigned short* Wb = (unsigned short*)(slot + (size_t)NN * MAXD); // 38912

    // 1. zero ELL counts (200 KB)
    hipMemsetAsync(counts, 0, (size_t)NN * sizeof(int), stream);
    // 2. fused: weights->bf16 (blocks [0,152)) + ELL fill ([152,152+FB))
    initfill_k<<<152 + FB, 256, 0, stream>>>(W1, W2, Wfc, Wb,
                                             esrc, edst, counts, slot, NE);
    // 3. layer-1 GEMM -> h
    gemm_mfma_f32in_k<<<GB, 256, 0, stream>>>(X, Wb, b1, h, NN);
    // 4. aggregate 128-wide -> x1b
    agg128_k<<<(NN * 64) / 256, 256, 0, stream>>>(h, counts, slot, x1b, NN);
    // 5. fused layer-2 GEMM + FC -> g
    gemm2fc_k<<<GB, 256, 0, stream>>>(x1b, Wb + 16384, b2, Wb + 32768, g, NN);
    // 6. aggregate 40-wide + bias -> out
    agg40_k<<<(NN * 64) / 256, 256, 0, stream>>>(g, counts, slot, bfc, out, NN);
}